// Round 1
// baseline (1324.765 us; speedup 1.0000x reference)
//
#include <hip/hip_runtime.h>

#define HH 100
#define G4 400      // 4*H
#define TT 256
#define BB 16
#define TB 4096     // T*B
#define VV 30522
#define VP 30528    // V padded to multiple of 64
#define KP 128      // K (=100) padded to multiple of 32
#define GX_ROWS 8

typedef unsigned short u16;
typedef __attribute__((ext_vector_type(8))) short s16x8;   // 8 bf16 = 4 VGPRs
typedef __attribute__((ext_vector_type(4))) float f32x4;

// float -> bf16 with round-to-nearest-even (finite inputs only)
__device__ __forceinline__ u16 f2bf(float x) {
    unsigned u = __float_as_uint(x);
    return (u16)((u + 0x7fffu + ((u >> 16) & 1u)) >> 16);
}
__device__ __forceinline__ float bf2f(u16 h) {
    return __uint_as_float((unsigned)h << 16);
}

// ---- transpose W_ih [400,100] -> [100,400] ----
__global__ void k_tw_ih(const float* __restrict__ W, float* __restrict__ Wt) {
    int idx = blockIdx.x * blockDim.x + threadIdx.x;
    if (idx < G4 * HH) {
        int j = idx / HH, k = idx - j * HH;
        Wt[k * G4 + j] = W[idx];
    }
}

// ---- split out_W [V,100] fp32 -> Bh/Bl bf16 [VP][KP] (zero-padded) ----
__global__ __launch_bounds__(256) void k_prep_w(const float* __restrict__ W,
                                                u16* __restrict__ Bh,
                                                u16* __restrict__ Bl) {
    int idx = blockIdx.x * 256 + threadIdx.x;   // VP*16 threads total
    int v = idx >> 4;
    int kc = (idx & 15) * 8;
    s16x8 vh, vl;
    #pragma unroll
    for (int j = 0; j < 8; ++j) {
        int k = kc + j;
        float x = (v < VV && k < HH) ? W[(long)v * HH + k] : 0.f;
        u16 hi = f2bf(x);
        vh[j] = (short)hi;
        vl[j] = (short)f2bf(x - bf2f(hi));
    }
    *(s16x8*)(Bh + (long)v * KP + kc) = vh;
    *(s16x8*)(Bl + (long)v * KP + kc) = vl;
}

// ---- gx[t,b,:] = emb[tok[t,b]] @ W_ih^T + b_ih + b_hh ----
__global__ __launch_bounds__(256) void k_gx(const int* __restrict__ tok,
                                            const float* __restrict__ emb,
                                            const float* __restrict__ WtIh,
                                            const float* __restrict__ bih,
                                            const float* __restrict__ bhh,
                                            float* __restrict__ gx) {
    __shared__ float x_s[GX_ROWS * HH];
    int tid = threadIdx.x;
    int row0 = blockIdx.x * GX_ROWS;
    for (int i = tid; i < GX_ROWS * HH; i += 256) {
        int r = i / HH, k = i - r * HH;
        x_s[i] = emb[(long)tok[row0 + r] * HH + k];
    }
    __syncthreads();
    for (int j = tid; j < G4; j += 256) {
        float bias = bih[j] + bhh[j];
        float acc[GX_ROWS];
        #pragma unroll
        for (int r = 0; r < GX_ROWS; ++r) acc[r] = bias;
        for (int k = 0; k < HH; ++k) {
            float w = WtIh[k * G4 + j];
            #pragma unroll
            for (int r = 0; r < GX_ROWS; ++r) acc[r] += w * x_s[r * HH + k];
        }
        #pragma unroll
        for (int r = 0; r < GX_ROWS; ++r) gx[(long)(row0 + r) * G4 + j] = acc[r];
    }
}

// ---- sequential decoder LSTM: one block per batch element ----
// Emits h directly as split-bf16 rows of A = [TB][KP] (hi and lo), k>=HH zeroed.
__global__ __launch_bounds__(512) void k_lstm(const float* __restrict__ gx,
                                              const float* __restrict__ Whh,
                                              u16* __restrict__ Ah,
                                              u16* __restrict__ Al) {
    __shared__ float h_s[HH];
    __shared__ float gates_s[G4];
    int tid = threadIdx.x;
    int b = blockIdx.x;
    float w[HH];
    if (tid < G4) {
        #pragma unroll
        for (int k = 0; k < HH; ++k) w[k] = Whh[tid * HH + k];
    }
    float c = 0.f;
    if (tid < HH) h_s[tid] = 0.f;
    __syncthreads();
    for (int t = 0; t < TT; ++t) {
        int row = t * BB + b;
        if (tid < G4) {
            float gxv = gx[(long)row * G4 + tid];
            float a0 = 0.f, a1 = 0.f, a2 = 0.f, a3 = 0.f;
            #pragma unroll
            for (int k = 0; k < HH; k += 4) {
                a0 += w[k]     * h_s[k];
                a1 += w[k + 1] * h_s[k + 1];
                a2 += w[k + 2] * h_s[k + 2];
                a3 += w[k + 3] * h_s[k + 3];
            }
            gates_s[tid] = gxv + ((a0 + a1) + (a2 + a3));
        }
        __syncthreads();
        if (tid < HH) {
            float gi = gates_s[tid];
            float gf = gates_s[HH + tid];
            float gg = gates_s[2 * HH + tid];
            float go = gates_s[3 * HH + tid];
            float si = 1.f / (1.f + expf(-gi));
            float sf = 1.f / (1.f + expf(-gf));
            float so = 1.f / (1.f + expf(-go));
            float tg = tanhf(gg);
            c = sf * c + si * tg;
            float h = so * tanhf(c);
            h_s[tid] = h;
            u16 hi = f2bf(h);
            Ah[(long)row * KP + tid] = hi;
            Al[(long)row * KP + tid] = f2bf(h - bf2f(hi));
        } else if (tid < KP) {
            Ah[(long)row * KP + tid] = 0;
            Al[(long)row * KP + tid] = 0;
        }
        __syncthreads();
    }
}

// ---- projection via MFMA, split-bf16 fp32 emulation ----
// out[m, v] = sum_k A[m,k] * W[v,k] + ob[v]
// A = Ah+Al (bf16 split of dec h), W = Bh+Bl (bf16 split of out_W)
// out ~= Ah.Bh + Ah.Bl + Al.Bh   (Al.Bl ~ 2^-18 relative, dropped)
// Block: 64(M) x 64(N) tile, 4 waves in 2x2; wave: 32x32 = 2x2 frags of 16x16.
// Both operand frags loaded with identical lane->k mapping (k = 8*(lane>>4)+j,
// contiguous 16B per lane) -> any internal HW k-permutation cancels in the dot.
// C/D layout (HW-verified): col = lane&15, row = (lane>>4)*4 + reg.
__global__ __launch_bounds__(256) void k_proj_mfma(const u16* __restrict__ Ah,
                                                   const u16* __restrict__ Al,
                                                   const u16* __restrict__ Bh,
                                                   const u16* __restrict__ Bl,
                                                   const float* __restrict__ ob,
                                                   float* __restrict__ out) {
    int tid  = threadIdx.x;
    int wid  = tid >> 6;
    int lane = tid & 63;
    int r    = lane & 15;
    int ko   = (lane >> 4) * 8;

    int m0 = blockIdx.y * 64 + (wid >> 1) * 32;
    int n0 = blockIdx.x * 64 + (wid & 1) * 32;

    const u16* pAh = Ah + (long)(m0 + r) * KP + ko;
    const u16* pAl = Al + (long)(m0 + r) * KP + ko;
    const u16* pBh = Bh + (long)(n0 + r) * KP + ko;
    const u16* pBl = Bl + (long)(n0 + r) * KP + ko;

    f32x4 acc00 = {0.f, 0.f, 0.f, 0.f};
    f32x4 acc01 = {0.f, 0.f, 0.f, 0.f};
    f32x4 acc10 = {0.f, 0.f, 0.f, 0.f};
    f32x4 acc11 = {0.f, 0.f, 0.f, 0.f};

    #pragma unroll
    for (int ks = 0; ks < 4; ++ks) {
        int off = ks * 32;
        s16x8 ah0 = *(const s16x8*)(pAh + off);
        s16x8 ah1 = *(const s16x8*)(pAh + off + 16 * KP);
        s16x8 al0 = *(const s16x8*)(pAl + off);
        s16x8 al1 = *(const s16x8*)(pAl + off + 16 * KP);
        s16x8 bh0 = *(const s16x8*)(pBh + off);
        s16x8 bh1 = *(const s16x8*)(pBh + off + 16 * KP);
        s16x8 bl0 = *(const s16x8*)(pBl + off);
        s16x8 bl1 = *(const s16x8*)(pBl + off + 16 * KP);
#define MM(d, a, b) d = __builtin_amdgcn_mfma_f32_16x16x32_bf16(a, b, d, 0, 0, 0)
        MM(acc00, ah0, bh0); MM(acc00, ah0, bl0); MM(acc00, al0, bh0);
        MM(acc01, ah0, bh1); MM(acc01, ah0, bl1); MM(acc01, al0, bh1);
        MM(acc10, ah1, bh0); MM(acc10, ah1, bl0); MM(acc10, al1, bh0);
        MM(acc11, ah1, bh1); MM(acc11, ah1, bl1); MM(acc11, al1, bh1);
#undef MM
    }

    int hi4 = (lane >> 4) * 4;
    int n_0 = n0 + r;
    int n_1 = n0 + 16 + r;
    bool ok0 = n_0 < VV;
    bool ok1 = n_1 < VV;
    float bias0 = ok0 ? ob[n_0] : 0.f;
    float bias1 = ok1 ? ob[n_1] : 0.f;
    long base0 = (long)(m0 + hi4) * VV;
    long base1 = (long)(m0 + 16 + hi4) * VV;

    if (ok0) {
        #pragma unroll
        for (int q = 0; q < 4; ++q) out[base0 + (long)q * VV + n_0] = acc00[q] + bias0;
        #pragma unroll
        for (int q = 0; q < 4; ++q) out[base1 + (long)q * VV + n_0] = acc10[q] + bias0;
    }
    if (ok1) {
        #pragma unroll
        for (int q = 0; q < 4; ++q) out[base0 + (long)q * VV + n_1] = acc01[q] + bias1;
        #pragma unroll
        for (int q = 0; q < 4; ++q) out[base1 + (long)q * VV + n_1] = acc11[q] + bias1;
    }
}

extern "C" void kernel_launch(void* const* d_in, const int* in_sizes, int n_in,
                              void* d_out, int out_size, void* d_ws, size_t ws_size,
                              hipStream_t stream) {
    const int*   tok  = (const int*)d_in[0];
    const float* emb  = (const float*)d_in[1];
    // d_in[2..5] = encoder weights: outputs unused by the reference -> skipped
    const float* dWih = (const float*)d_in[6];
    const float* dWhh = (const float*)d_in[7];
    const float* dbih = (const float*)d_in[8];
    const float* dbhh = (const float*)d_in[9];
    const float* outW = (const float*)d_in[10];
    const float* outb = (const float*)d_in[11];
    float* out = (float*)d_out;

    // Workspace layout (bytes):
    //   [Ah: TB*KP*2 = 1 MB][Al: 1 MB][WtIh: 100*400*4 = 160 KB]
    //   [shared region: gx (TB*G4*4 = 6.55 MB)  -- later reused as Bh+Bl (15.63 MB)]
    // total 17.9 MB < 20.6 MB used by the previous (passing) version.
    u16* Ah = (u16*)d_ws;
    u16* Al = Ah + (long)TB * KP;
    float* WtIh = (float*)(Al + (long)TB * KP);
    char* big = (char*)(WtIh + (long)HH * G4);
    float* gx = (float*)big;                 // alive: k_gx -> k_lstm
    u16* Bh = (u16*)big;                     // alive: k_prep_w -> k_proj (after gx dead)
    u16* Bl = Bh + (long)VP * KP;

    k_tw_ih<<<(G4 * HH + 255) / 256, 256, 0, stream>>>(dWih, WtIh);
    k_gx<<<TB / GX_ROWS, 256, 0, stream>>>(tok, emb, WtIh, dbih, dbhh, gx);
    k_lstm<<<BB, 512, 0, stream>>>(gx, dWhh, Ah, Al);
    // after k_lstm, gx is dead -> safe to overwrite with Bh/Bl (same stream)
    k_prep_w<<<(VP * 16) / 256, 256, 0, stream>>>(outW, Bh, Bl);
    k_proj_mfma<<<dim3(VP / 64, TB / 64), 256, 0, stream>>>(Ah, Al, Bh, Bl, outb, out);
}

// Round 2
// 1317.876 us; speedup vs baseline: 1.0052x; 1.0052x over previous
//
#include <hip/hip_runtime.h>

#define HH 100
#define G4 400      // 4*H
#define TT 256
#define BB 16
#define TB 4096     // T*B
#define VV 30522
#define VP 30720    // V padded to 480 n-tiles of 64 (divisible by 8 XCD chunks)
#define KP 128      // K (=100) padded to multiple of 32
#define GX_ROWS 8

typedef unsigned short u16;
typedef __attribute__((ext_vector_type(8))) short s16x8;   // 8 bf16 = 4 VGPRs
typedef __attribute__((ext_vector_type(4))) float f32x4;

// float -> bf16 with round-to-nearest-even (finite inputs only)
__device__ __forceinline__ u16 f2bf(float x) {
    unsigned u = __float_as_uint(x);
    return (u16)((u + 0x7fffu + ((u >> 16) & 1u)) >> 16);
}
__device__ __forceinline__ float bf2f(u16 h) {
    return __uint_as_float((unsigned)h << 16);
}

#define MM(d, a, b) d = __builtin_amdgcn_mfma_f32_16x16x32_bf16(a, b, d, 0, 0, 0)

// ---- transpose W_ih [400,100] -> [100,400] ----
__global__ void k_tw_ih(const float* __restrict__ W, float* __restrict__ Wt) {
    int idx = blockIdx.x * blockDim.x + threadIdx.x;
    if (idx < G4 * HH) {
        int j = idx / HH, k = idx - j * HH;
        Wt[k * G4 + j] = W[idx];
    }
}

// ---- split out_W [V,100] fp32 -> Bh/Bl bf16 [VP][KP] (zero-padded) ----
__global__ __launch_bounds__(256) void k_prep_w(const float* __restrict__ W,
                                                u16* __restrict__ Bh,
                                                u16* __restrict__ Bl) {
    int idx = blockIdx.x * 256 + threadIdx.x;   // VP*16 threads total
    int v = idx >> 4;
    int kc = (idx & 15) * 8;
    s16x8 vh, vl;
    #pragma unroll
    for (int j = 0; j < 8; ++j) {
        int k = kc + j;
        float x = (v < VV && k < HH) ? W[(long)v * HH + k] : 0.f;
        u16 hi = f2bf(x);
        vh[j] = (short)hi;
        vl[j] = (short)f2bf(x - bf2f(hi));
    }
    *(s16x8*)(Bh + (long)v * KP + kc) = vh;
    *(s16x8*)(Bl + (long)v * KP + kc) = vl;
}

// ---- gx[t,b,:] = emb[tok[t,b]] @ W_ih^T + b_ih + b_hh ----
__global__ __launch_bounds__(256) void k_gx(const int* __restrict__ tok,
                                            const float* __restrict__ emb,
                                            const float* __restrict__ WtIh,
                                            const float* __restrict__ bih,
                                            const float* __restrict__ bhh,
                                            float* __restrict__ gx) {
    __shared__ float x_s[GX_ROWS * HH];
    int tid = threadIdx.x;
    int row0 = blockIdx.x * GX_ROWS;
    for (int i = tid; i < GX_ROWS * HH; i += 256) {
        int r = i / HH, k = i - r * HH;
        x_s[i] = emb[(long)tok[row0 + r] * HH + k];
    }
    __syncthreads();
    for (int j = tid; j < G4; j += 256) {
        float bias = bih[j] + bhh[j];
        float acc[GX_ROWS];
        #pragma unroll
        for (int r = 0; r < GX_ROWS; ++r) acc[r] = bias;
        for (int k = 0; k < HH; ++k) {
            float w = WtIh[k * G4 + j];
            #pragma unroll
            for (int r = 0; r < GX_ROWS; ++r) acc[r] += w * x_s[r * HH + k];
        }
        #pragma unroll
        for (int r = 0; r < GX_ROWS; ++r) gx[(long)(row0 + r) * G4 + j] = acc[r];
    }
}

// ---- sequential decoder LSTM via per-batch MFMA matvec ----
// One block per batch element (16 blocks, 512 threads = 8 waves).
// gates_mv[400] = Whh @ h, computed as split-bf16 MFMA (err ~2^-18 rel):
//   A = Whh (hi+lo) in per-wave VGPR fragments, preloaded once.
//   B[k][c] = h[k] for ALL cols c (broadcast LDS read) -> every D col is valid.
// Wave w owns m-tiles {w, w+8, w+16, (24 if w==0)}; lanes with (lane&15)==0
// scatter D rows (lane>>4)*4+q to LDS via one ds_write_b128 per tile.
// Fragment mapping identical to harness-validated k_proj_mfma usage.
__global__ __launch_bounds__(512) void k_lstm(const float* __restrict__ gx,
                                              const float* __restrict__ Whh,
                                              u16* __restrict__ Ah,
                                              u16* __restrict__ Al) {
    __shared__ __align__(16) float gmv[G4];
    __shared__ __align__(16) u16 hhi[KP];
    __shared__ __align__(16) u16 hlo[KP];
    int tid = threadIdx.x;
    int w = tid >> 6, l = tid & 63;
    int b = blockIdx.x;
    int r = l & 15;
    int ks8 = (l >> 4) * 8;            // k offset within a 32-k tile

    // ---- one-time: load + split Whh fragments ----
    int mts[4];
    int ntile = 0;
    for (int mt = w; mt < 25; mt += 8) mts[ntile++] = mt;
    s16x8 Afh[4][4], Afl[4][4];        // [tile][kt]
    #pragma unroll
    for (int i = 0; i < 4; ++i) {
        #pragma unroll
        for (int kt = 0; kt < 4; ++kt) {
            s16x8 vh = {0,0,0,0,0,0,0,0}, vl = {0,0,0,0,0,0,0,0};
            if (i < ntile) {
                int row = mts[i] * 16 + r;
                int k0 = kt * 32 + ks8;
                #pragma unroll
                for (int j = 0; j < 8; ++j) {
                    int k = k0 + j;
                    float x = (k < HH) ? Whh[row * HH + k] : 0.f;
                    u16 hi = f2bf(x);
                    vh[j] = (short)hi;
                    vl[j] = (short)f2bf(x - bf2f(hi));
                }
            }
            Afh[i][kt] = vh;
            Afl[i][kt] = vl;
        }
    }

    float c_reg = 0.f;
    if (tid < KP) { hhi[tid] = 0; hlo[tid] = 0; }
    __syncthreads();

    for (int t = 0; t < TT; ++t) {
        int row = t * BB + b;
        // B-fragments: broadcast h (same 16B for all lanes of a wave)
        s16x8 Bh_[4], Bl_[4];
        #pragma unroll
        for (int kt = 0; kt < 4; ++kt) {
            Bh_[kt] = *(const s16x8*)&hhi[kt * 32 + ks8];
            Bl_[kt] = *(const s16x8*)&hlo[kt * 32 + ks8];
        }
        // hoist gx loads (hide HBM/L2 latency under MFMA phase)
        float gxv0 = 0.f, gxv1 = 0.f, gxv2 = 0.f, gxv3 = 0.f;
        if (tid < HH) {
            const float* gxr = gx + (long)row * G4 + tid;
            gxv0 = gxr[0];
            gxv1 = gxr[HH];
            gxv2 = gxr[2 * HH];
            gxv3 = gxr[3 * HH];
        }
        // 3 independent accumulator chains per tile (short dep chains)
        f32x4 aH[4], aM[4], aL[4];
        #pragma unroll
        for (int i = 0; i < 4; ++i) {
            aH[i] = f32x4{0.f, 0.f, 0.f, 0.f};
            aM[i] = f32x4{0.f, 0.f, 0.f, 0.f};
            aL[i] = f32x4{0.f, 0.f, 0.f, 0.f};
        }
        #pragma unroll
        for (int i = 0; i < 4; ++i) {
            if (i < ntile) {
                #pragma unroll
                for (int kt = 0; kt < 4; ++kt) {
                    MM(aH[i], Afh[i][kt], Bh_[kt]);
                    MM(aM[i], Afh[i][kt], Bl_[kt]);
                    MM(aL[i], Afl[i][kt], Bh_[kt]);
                }
            }
        }
        if (r == 0) {
            #pragma unroll
            for (int i = 0; i < 4; ++i) {
                if (i < ntile) {
                    f32x4 s = aH[i] + aM[i] + aL[i];
                    *(f32x4*)&gmv[mts[i] * 16 + (l >> 4) * 4] = s;
                }
            }
        }
        __syncthreads();
        if (tid < HH) {
            float gi = gmv[tid]          + gxv0;
            float gf = gmv[HH + tid]     + gxv1;
            float gg = gmv[2 * HH + tid] + gxv2;
            float go = gmv[3 * HH + tid] + gxv3;
            float si = 1.f / (1.f + expf(-gi));
            float sf = 1.f / (1.f + expf(-gf));
            float so = 1.f / (1.f + expf(-go));
            float tg = tanhf(gg);
            c_reg = sf * c_reg + si * tg;
            float h = so * tanhf(c_reg);
            u16 hi = f2bf(h);
            u16 lo = f2bf(h - bf2f(hi));
            hhi[tid] = hi;
            hlo[tid] = lo;
            Ah[(long)row * KP + tid] = hi;
            Al[(long)row * KP + tid] = lo;
        } else if (tid < KP) {
            Ah[(long)row * KP + tid] = 0;
            Al[(long)row * KP + tid] = 0;
        }
        __syncthreads();
    }
}

// ---- projection via MFMA, split-bf16 fp32 emulation ----
// out[m, v] = sum_k A[m,k] * W[v,k] + ob[v]
// Grid: 1-D, XCD-chunked swizzle. xcd = id%8 owns a contiguous chunk of 60
// n-tiles (B-chunk 1.97 MB -> L2-resident per XCD); within a chunk n sweeps
// fastest, so B is fetched from HBM once and A (2 MB) streams via L2/L3.
// Output stores are nontemporal so the 565 MB write stream doesn't evict B.
__global__ __launch_bounds__(256) void k_proj_mfma(const u16* __restrict__ Ah,
                                                   const u16* __restrict__ Al,
                                                   const u16* __restrict__ Bh,
                                                   const u16* __restrict__ Bl,
                                                   const float* __restrict__ ob,
                                                   float* __restrict__ out) {
    int tid  = threadIdx.x;
    int wid  = tid >> 6;
    int lane = tid & 63;
    int r    = lane & 15;
    int ko   = (lane >> 4) * 8;

    int id  = blockIdx.x;
    int xcd = id & 7;
    int j   = id >> 3;                 // 0..3839
    int nt  = xcd * 60 + (j % 60);     // n-tile 0..479
    int mt  = j / 60;                  // m-tile 0..63

    int m0 = mt * 64 + (wid >> 1) * 32;
    int n0 = nt * 64 + (wid & 1) * 32;

    const u16* pAh = Ah + (long)(m0 + r) * KP + ko;
    const u16* pAl = Al + (long)(m0 + r) * KP + ko;
    const u16* pBh = Bh + (long)(n0 + r) * KP + ko;
    const u16* pBl = Bl + (long)(n0 + r) * KP + ko;

    f32x4 acc00 = {0.f, 0.f, 0.f, 0.f};
    f32x4 acc01 = {0.f, 0.f, 0.f, 0.f};
    f32x4 acc10 = {0.f, 0.f, 0.f, 0.f};
    f32x4 acc11 = {0.f, 0.f, 0.f, 0.f};

    #pragma unroll
    for (int ks = 0; ks < 4; ++ks) {
        int off = ks * 32;
        s16x8 ah0 = *(const s16x8*)(pAh + off);
        s16x8 ah1 = *(const s16x8*)(pAh + off + 16 * KP);
        s16x8 al0 = *(const s16x8*)(pAl + off);
        s16x8 al1 = *(const s16x8*)(pAl + off + 16 * KP);
        s16x8 bh0 = *(const s16x8*)(pBh + off);
        s16x8 bh1 = *(const s16x8*)(pBh + off + 16 * KP);
        s16x8 bl0 = *(const s16x8*)(pBl + off);
        s16x8 bl1 = *(const s16x8*)(pBl + off + 16 * KP);
        MM(acc00, ah0, bh0); MM(acc00, ah0, bl0); MM(acc00, al0, bh0);
        MM(acc01, ah0, bh1); MM(acc01, ah0, bl1); MM(acc01, al0, bh1);
        MM(acc10, ah1, bh0); MM(acc10, ah1, bl0); MM(acc10, al1, bh0);
        MM(acc11, ah1, bh1); MM(acc11, ah1, bl1); MM(acc11, al1, bh1);
    }

    int hi4 = (lane >> 4) * 4;
    int n_0 = n0 + r;
    int n_1 = n0 + 16 + r;
    bool ok0 = n_0 < VV;
    bool ok1 = n_1 < VV;
    float bias0 = ok0 ? ob[n_0] : 0.f;
    float bias1 = ok1 ? ob[n_1] : 0.f;
    long base0 = (long)(m0 + hi4) * VV;
    long base1 = (long)(m0 + 16 + hi4) * VV;

    // interleave n_0/n_1 stores per row so the two 64B halves of each 128B
    // line are adjacent in program order (write-combine friendly)
    #pragma unroll
    for (int q = 0; q < 4; ++q) {
        if (ok0) __builtin_nontemporal_store(acc00[q] + bias0, &out[base0 + (long)q * VV + n_0]);
        if (ok1) __builtin_nontemporal_store(acc01[q] + bias1, &out[base0 + (long)q * VV + n_1]);
    }
    #pragma unroll
    for (int q = 0; q < 4; ++q) {
        if (ok0) __builtin_nontemporal_store(acc10[q] + bias0, &out[base1 + (long)q * VV + n_0]);
        if (ok1) __builtin_nontemporal_store(acc11[q] + bias1, &out[base1 + (long)q * VV + n_1]);
    }
}

extern "C" void kernel_launch(void* const* d_in, const int* in_sizes, int n_in,
                              void* d_out, int out_size, void* d_ws, size_t ws_size,
                              hipStream_t stream) {
    const int*   tok  = (const int*)d_in[0];
    const float* emb  = (const float*)d_in[1];
    // d_in[2..5] = encoder weights: outputs unused by the reference -> skipped
    const float* dWih = (const float*)d_in[6];
    const float* dWhh = (const float*)d_in[7];
    const float* dbih = (const float*)d_in[8];
    const float* dbhh = (const float*)d_in[9];
    const float* outW = (const float*)d_in[10];
    const float* outb = (const float*)d_in[11];
    float* out = (float*)d_out;

    // Workspace layout (bytes):
    //   [Ah: TB*KP*2 = 1 MB][Al: 1 MB][WtIh: 160 KB]
    //   [shared region: gx (6.55 MB) -- later reused as Bh+Bl (15.73 MB)]
    // total ~17.9 MB (fits: previous passing versions used this budget).
    u16* Ah = (u16*)d_ws;
    u16* Al = Ah + (long)TB * KP;
    float* WtIh = (float*)(Al + (long)TB * KP);
    char* big = (char*)(WtIh + (long)HH * G4);
    float* gx = (float*)big;                 // alive: k_gx -> k_lstm
    u16* Bh = (u16*)big;                     // alive: k_prep_w -> k_proj (after gx dead)
    u16* Bl = Bh + (long)VP * KP;

    k_tw_ih<<<(G4 * HH + 255) / 256, 256, 0, stream>>>(dWih, WtIh);
    k_gx<<<TB / GX_ROWS, 256, 0, stream>>>(tok, emb, WtIh, dbih, dbhh, gx);
    k_lstm<<<BB, 512, 0, stream>>>(gx, dWhh, Ah, Al);
    // after k_lstm, gx is dead -> safe to overwrite with Bh/Bl (same stream)
    k_prep_w<<<(VP * 16) / 256, 256, 0, stream>>>(outW, Bh, Bl);
    k_proj_mfma<<<VP / 64 * (TB / 64), 256, 0, stream>>>(Ah, Al, Bh, Bl, outb, out);
}